// Round 2
// baseline (137.688 us; speedup 1.0000x reference)
//
#include <hip/hip_runtime.h>
#include <hip/hip_bf16.h>
#include <stdint.h>

// Problem constants: x[16,256,64,64] f32; fc1[65,256]; fc2[1024,65]; fc2_b[1024];
// weight[4,256,256,3,3]; out[16,256,64,64] f32.

typedef __bf16 bf16x8 __attribute__((ext_vector_type(8)));
typedef float  f32x4  __attribute__((ext_vector_type(4)));

__device__ __forceinline__ unsigned short f2bf(float f) {
  union { float f; unsigned u; } v; v.f = f;
  return (unsigned short)((v.u + 0x7FFFu + ((v.u >> 16) & 1u)) >> 16);
}

__device__ __forceinline__ void gload16(const void* g, void* l) {
  __builtin_amdgcn_global_load_lds(
      (const __attribute__((address_space(1))) void*)g,
      (__attribute__((address_space(3))) void*)l, 16, 0, 0);
}

// ---------------- Kernel A: pooling + NCHW f32 -> NHWC bf16 ----------------
// grid: 16 b * 4 cchunk * 64 y = 4096 blocks, 256 threads
__global__ __launch_bounds__(256) void k_prep(
    const float* __restrict__ x, unsigned short* __restrict__ xn,
    float* __restrict__ pooled_sum) {
  const int bx = blockIdx.x;
  const int y  = bx & 63;
  const int cc = (bx >> 6) & 3;
  const int b  = bx >> 8;
  const int t  = threadIdx.x;
  const int cl = t >> 2;    // channel-in-chunk 0..63
  const int q  = t & 3;     // 16-float segment
  const int xs = q * 16;

  const float4* s4 = (const float4*)(x + (((size_t)(b * 256 + cc * 64 + cl) * 64 + y) * 64 + xs));
  float v[16];
#pragma unroll
  for (int i = 0; i < 4; ++i) {
    float4 f = s4[i];
    v[i * 4 + 0] = f.x; v[i * 4 + 1] = f.y; v[i * 4 + 2] = f.z; v[i * 4 + 3] = f.w;
  }
  float s = 0.f;
#pragma unroll
  for (int i = 0; i < 16; ++i) s += v[i];
  s += __shfl_xor(s, 1);
  s += __shfl_xor(s, 2);
  if (q == 0) atomicAdd(&pooled_sum[b * 256 + cc * 64 + cl], s);

  __shared__ unsigned short tile[64][72];   // [x][c], padded
#pragma unroll
  for (int j = 0; j < 16; ++j) tile[xs + j][cl] = f2bf(v[j]);
  __syncthreads();
  const int xp = t >> 2;
  const uint4* ls = (const uint4*)&tile[xp][q * 16];
  uint4 a0 = ls[0], a1 = ls[1];
  uint4* gd = (uint4*)(xn + ((size_t)((b * 64 + y) * 64 + xp) * 256 + cc * 64 + q * 16));
  gd[0] = a0; gd[1] = a1;
}

// ---------------- Kernel B1: fc1 -> relu -> fc2 -> softmax/T -> prob ----------------
// grid: 16 blocks (one per sample), 256 threads
__global__ __launch_bounds__(256) void k_fc(
    const float* __restrict__ pooled_sum,
    const float* __restrict__ fc1, const float* __restrict__ fc2,
    const float* __restrict__ fc2b, float* __restrict__ prob) {
  const int b = blockIdx.x, t = threadIdx.x;
  __shared__ float p[256];
  __shared__ float h[72];
  __shared__ float yv[1024];
  p[t] = pooled_sum[b * 256 + t] * (1.0f / 4096.0f);
  __syncthreads();
  if (t < 65) {
    float s = 0.f;
    for (int c = 0; c < 256; ++c) s += p[c] * fc1[t * 256 + c];
    h[t] = fmaxf(s, 0.f);
  }
  __syncthreads();
  for (int m = t; m < 1024; m += 256) {
    float s = fc2b[m];
    for (int j = 0; j < 65; ++j) s += h[j] * fc2[m * 65 + j];
    yv[m] = s;
  }
  __syncthreads();
  const float invT = 1.0f / 30.0f;
  float e0 = yv[t] * invT, e1 = yv[256 + t] * invT, e2 = yv[512 + t] * invT, e3 = yv[768 + t] * invT;
  float mx = fmaxf(fmaxf(e0, e1), fmaxf(e2, e3));
  float x0 = expf(e0 - mx), x1 = expf(e1 - mx), x2 = expf(e2 - mx), x3 = expf(e3 - mx);
  float r = 1.0f / (x0 + x1 + x2 + x3);
  prob[(b * 4 + 0) * 256 + t] = x0 * r;
  prob[(b * 4 + 1) * 256 + t] = x1 * r;
  prob[(b * 4 + 2) * 256 + t] = x2 * r;
  prob[(b * 4 + 3) * 256 + t] = x3 * r;
}

// ---------------- Kernel B2: aggT[b][tap][o][c] bf16 = sum_k prob*weight ----------------
// grid: 256 blocks (one per o), 256 threads
__global__ __launch_bounds__(256) void k_agg(
    const float* __restrict__ weight, const float* __restrict__ prob,
    unsigned short* __restrict__ aggT) {
  const int o = blockIdx.x, t = threadIdx.x;
  __shared__ float w[4][2304];
#pragma unroll
  for (int k = 0; k < 4; ++k) {
    const float4* src = (const float4*)(weight + (size_t)(k * 256 + o) * 2304);
    float4* dst = (float4*)w[k];
    for (int j = t; j < 576; j += 256) dst[j] = src[j];
  }
  __syncthreads();
  const int c = t;
  float wv[4][9];
#pragma unroll
  for (int k = 0; k < 4; ++k)
#pragma unroll
    for (int tap = 0; tap < 9; ++tap) wv[k][tap] = w[k][c * 9 + tap];
  for (int b = 0; b < 16; ++b) {
    float p0 = prob[(b * 4 + 0) * 256 + o];
    float p1 = prob[(b * 4 + 1) * 256 + o];
    float p2 = prob[(b * 4 + 2) * 256 + o];
    float p3 = prob[(b * 4 + 3) * 256 + o];
#pragma unroll
    for (int tap = 0; tap < 9; ++tap) {
      float vv = p0 * wv[0][tap] + p1 * wv[1][tap] + p2 * wv[2][tap] + p3 * wv[3][tap];
      aggT[((size_t)(b * 9 + tap) * 256 + o) * 256 + c] = f2bf(vv);
    }
  }
}

// ---------------- Kernel C: per-sample implicit-GEMM conv ----------------
// Tile: 128 pixels (2 rows x 64 cols) x 128 out-channels. 4 waves (2x2).
// K-loop: 4 c-chunks(64) x 9 taps x 2 MFMA K-steps (16x16x32 bf16).
// X LDS [pos=rr*64+xc (256)][c 64], W LDS [o 128][c 64], both XOR-swizzled
// (unit ^= row&7) via pre-swizzled global_load_lds source.
// grid: 16 b * 32 ytile * 2 otile = 1024 blocks, 256 threads
__global__ __launch_bounds__(256, 2) void k_conv(
    const unsigned short* __restrict__ xn,
    const unsigned short* __restrict__ aggT,
    const unsigned short* __restrict__ zpage,
    float* __restrict__ out) {
  const int bx = blockIdx.x;
  const int ot = bx & 1;
  const int yt = (bx >> 1) & 31;
  const int b  = bx >> 6;
  const int y0 = yt * 2;
  const int o0 = ot * 128;
  const int t    = threadIdx.x;
  const int lane = t & 63;
  const int l15  = lane & 15;
  const int lg   = lane >> 4;
  const int wid  = t >> 6;
  const int wm   = wid >> 1;   // pixel row of wave (0..1)
  const int wn   = wid & 1;    // ochan half (0..1)

  __shared__ unsigned short xbuf[256 * 64];      // 32 KiB
  __shared__ unsigned short wbuf[2][128 * 64];   // 2 x 16 KiB

  const f32x4 vzero = {0.f, 0.f, 0.f, 0.f};
  const bf16x8 bzero = {};
  f32x4 acc[4][4];
#pragma unroll
  for (int i = 0; i < 4; ++i)
#pragma unroll
    for (int j = 0; j < 4; ++j) acc[i][j] = vzero;

  const unsigned short* xb = xn + (size_t)b * (64 * 64 * 256);
  const unsigned short* ab = aggT + (size_t)b * (9 * 256 * 256) + (size_t)o0 * 256;

  for (int cc = 0; cc < 4; ++cc) {
    const int c0 = cc * 64;
    // stage X tile (2048 x 16B units), row halo -> zero page
#pragma unroll
    for (int i = 0; i < 8; ++i) {
      int u = t + i * 256;
      int pos = u >> 3, s = u & 7;
      int rr = pos >> 6, xc = pos & 63;
      int yy = y0 - 1 + rr;
      int sp = (s ^ (pos & 7)) * 8;
      const unsigned short* src = (yy >= 0 && yy < 64)
          ? xb + ((size_t)yy * 64 + xc) * 256 + (c0 + sp)
          : zpage + ((u & 127) * 8);
      gload16(src, &xbuf[u * 8]);
    }
    // stage W tap 0 (1024 x 16B units)
#pragma unroll
    for (int i = 0; i < 4; ++i) {
      int u = t + i * 256;
      int o = u >> 3, s = u & 7;
      gload16(ab + (size_t)o * 256 + c0 + ((s ^ (o & 7)) * 8), &wbuf[0][u * 8]);
    }
    __syncthreads();

#pragma unroll
    for (int tap = 0; tap < 9; ++tap) {
      if (tap < 8) {   // prefetch W(t+1) into the other buffer; latency hides under MFMAs
        const unsigned short* wsrc = ab + (size_t)(tap + 1) * (256 * 256) + c0;
#pragma unroll
        for (int i = 0; i < 4; ++i) {
          int u = t + i * 256;
          int o = u >> 3, s = u & 7;
          gload16(wsrc + (size_t)o * 256 + ((s ^ (o & 7)) * 8), &wbuf[(tap + 1) & 1][u * 8]);
        }
      }
      const int kh = tap / 3;
      const int d  = tap % 3 - 1;
      const int prow = (wm + kh) * 64;
      const unsigned short* wb = wbuf[tap & 1];
#pragma unroll
      for (int ku = 0; ku < 2; ++ku) {
        bf16x8 av[4], bv[4];
#pragma unroll
        for (int mf = 0; mf < 4; ++mf) {
          int xsrc = mf * 16 + l15 + d;
          bool valid = (xsrc >= 0) && (xsrc < 64);
          int xcl = min(max(xsrc, 0), 63);
          int pos = prow + xcl;
          int su = (ku * 4 + lg) ^ (pos & 7);
          av[mf] = *(const bf16x8*)&xbuf[pos * 64 + su * 8];
          if (!valid) av[mf] = bzero;   // column halo -> 0
        }
#pragma unroll
        for (int nf = 0; nf < 4; ++nf) {
          int oo = wn * 64 + nf * 16 + l15;
          int su = (ku * 4 + lg) ^ (oo & 7);
          bv[nf] = *(const bf16x8*)&wb[oo * 64 + su * 8];
        }
#pragma unroll
        for (int mf = 0; mf < 4; ++mf)
#pragma unroll
          for (int nf = 0; nf < 4; ++nf)
            acc[mf][nf] = __builtin_amdgcn_mfma_f32_16x16x32_bf16(av[mf], bv[nf], acc[mf][nf], 0, 0, 0);
      }
      __syncthreads();   // drains vmcnt (W prefetch) + lets everyone finish reading wbuf
    }
  }

  // epilogue: D row = pixel = (lane>>4)*4 + reg, col = ochan = lane&15
  const int yrow = y0 + wm;
#pragma unroll
  for (int nf = 0; nf < 4; ++nf) {
    int och = o0 + wn * 64 + nf * 16 + l15;
    float* op = out + ((size_t)(b * 256 + och) * 4096) + yrow * 64;
#pragma unroll
    for (int mf = 0; mf < 4; ++mf) {
      int xcb = mf * 16 + lg * 4;
      *(float4*)(op + xcb) = *(float4*)&acc[mf][nf];
    }
  }
}

extern "C" void kernel_launch(void* const* d_in, const int* in_sizes, int n_in,
                              void* d_out, int out_size, void* d_ws, size_t ws_size,
                              hipStream_t stream) {
  (void)in_sizes; (void)n_in; (void)out_size; (void)ws_size;
  const float* x      = (const float*)d_in[0];
  const float* fc1    = (const float*)d_in[1];
  const float* fc2    = (const float*)d_in[2];
  const float* fc2b   = (const float*)d_in[3];
  const float* weight = (const float*)d_in[4];
  float* out = (float*)d_out;

  // workspace layout (~52.7 MB):
  //   [0,4K)            zero page (row-halo source for global_load_lds)
  //   [4K,20K)          pooled_sum f32[16][256]            (16,384 B)
  //   [20K, 86016)      prob f32[16][4][256]               (65,536 B)
  //   [131072, +18.87MB)  aggT bf16[16][9][256][256]       (18,874,368 B)
  //   [19,005,440, +33.55MB) x_nhwc bf16[16][64][64][256]  (33,554,432 B)
  char* ws = (char*)d_ws;
  unsigned short* zpage  = (unsigned short*)ws;
  float*          pooled = (float*)(ws + 4096);
  float*          prob   = (float*)(ws + 20480);
  unsigned short* aggT   = (unsigned short*)(ws + 131072);
  unsigned short* xnhwc  = (unsigned short*)(ws + 131072 + 18874368);

  hipMemsetAsync(d_ws, 0, 20480, stream);  // zero page + pooled_sum, every launch
  k_prep<<<dim3(16 * 4 * 64), dim3(256), 0, stream>>>(x, xnhwc, pooled);
  k_fc  <<<dim3(16),          dim3(256), 0, stream>>>(pooled, fc1, fc2, fc2b, prob);
  k_agg <<<dim3(256),         dim3(256), 0, stream>>>(weight, prob, aggT);
  k_conv<<<dim3(1024),        dim3(256), 0, stream>>>(xnhwc, aggT, zpage, out);
}

// Round 3
// 132.996 us; speedup vs baseline: 1.0353x; 1.0353x over previous
//
#include <hip/hip_runtime.h>
#include <hip/hip_bf16.h>
#include <stdint.h>

// Problem constants: x[16,256,64,64] f32; fc1[65,256]; fc2[1024,65]; fc2_b[1024];
// weight[4,256,256,3,3]; out[16,256,64,64] f32.

typedef __bf16 bf16x8 __attribute__((ext_vector_type(8)));
typedef float  f32x4  __attribute__((ext_vector_type(4)));

__device__ __forceinline__ unsigned short f2bf(float f) {
  union { float f; unsigned u; } v; v.f = f;
  return (unsigned short)((v.u + 0x7FFFu + ((v.u >> 16) & 1u)) >> 16);
}

__device__ __forceinline__ void gload16(const void* g, void* l) {
  __builtin_amdgcn_global_load_lds(
      (const __attribute__((address_space(1))) void*)g,
      (__attribute__((address_space(3))) void*)l, 16, 0, 0);
}

// counted waits + pinned barrier (T3/T4 pattern; sched_barrier pins against
// hoisting ds_reads above s_barrier -> cross-wave race otherwise)
#define WAIT_VM(N) do { __builtin_amdgcn_sched_barrier(0); \
  asm volatile("s_waitcnt vmcnt(" #N ")" ::: "memory"); \
  __builtin_amdgcn_sched_barrier(0); } while (0)
#define BARRIER_PIN() do { __builtin_amdgcn_s_barrier(); \
  __builtin_amdgcn_sched_barrier(0); } while (0)

// ---------------- Kernel A: pooling + NCHW f32 -> NHWC bf16 ----------------
// grid: 16 b * 4 cchunk * 64 y = 4096 blocks, 256 threads
__global__ __launch_bounds__(256) void k_prep(
    const float* __restrict__ x, unsigned short* __restrict__ xn,
    float* __restrict__ pooled_sum) {
  const int bx = blockIdx.x;
  const int y  = bx & 63;
  const int cc = (bx >> 6) & 3;
  const int b  = bx >> 8;
  const int t  = threadIdx.x;
  const int cl = t >> 2;    // channel-in-chunk 0..63
  const int q  = t & 3;     // 16-float segment
  const int xs = q * 16;

  const float4* s4 = (const float4*)(x + (((size_t)(b * 256 + cc * 64 + cl) * 64 + y) * 64 + xs));
  float v[16];
#pragma unroll
  for (int i = 0; i < 4; ++i) {
    float4 f = s4[i];
    v[i * 4 + 0] = f.x; v[i * 4 + 1] = f.y; v[i * 4 + 2] = f.z; v[i * 4 + 3] = f.w;
  }
  float s = 0.f;
#pragma unroll
  for (int i = 0; i < 16; ++i) s += v[i];
  s += __shfl_xor(s, 1);
  s += __shfl_xor(s, 2);
  if (q == 0) atomicAdd(&pooled_sum[b * 256 + cc * 64 + cl], s);

  __shared__ unsigned short tile[64][72];   // [x][c], padded
#pragma unroll
  for (int j = 0; j < 16; ++j) tile[xs + j][cl] = f2bf(v[j]);
  __syncthreads();
  const int xp = t >> 2;
  const uint4* ls = (const uint4*)&tile[xp][q * 16];
  uint4 a0 = ls[0], a1 = ls[1];
  uint4* gd = (uint4*)(xn + ((size_t)((b * 64 + y) * 64 + xp) * 256 + cc * 64 + q * 16));
  gd[0] = a0; gd[1] = a1;
}

// ---------------- Kernel B1: fc1 -> relu -> fc2 -> softmax/T -> prob ----------------
__global__ __launch_bounds__(256) void k_fc(
    const float* __restrict__ pooled_sum,
    const float* __restrict__ fc1, const float* __restrict__ fc2,
    const float* __restrict__ fc2b, float* __restrict__ prob) {
  const int b = blockIdx.x, t = threadIdx.x;
  __shared__ float p[256];
  __shared__ float h[72];
  __shared__ float yv[1024];
  p[t] = pooled_sum[b * 256 + t] * (1.0f / 4096.0f);
  __syncthreads();
  if (t < 65) {
    float s = 0.f;
    for (int c = 0; c < 256; ++c) s += p[c] * fc1[t * 256 + c];
    h[t] = fmaxf(s, 0.f);
  }
  __syncthreads();
  for (int m = t; m < 1024; m += 256) {
    float s = fc2b[m];
    for (int j = 0; j < 65; ++j) s += h[j] * fc2[m * 65 + j];
    yv[m] = s;
  }
  __syncthreads();
  const float invT = 1.0f / 30.0f;
  float e0 = yv[t] * invT, e1 = yv[256 + t] * invT, e2 = yv[512 + t] * invT, e3 = yv[768 + t] * invT;
  float mx = fmaxf(fmaxf(e0, e1), fmaxf(e2, e3));
  float x0 = expf(e0 - mx), x1 = expf(e1 - mx), x2 = expf(e2 - mx), x3 = expf(e3 - mx);
  float r = 1.0f / (x0 + x1 + x2 + x3);
  prob[(b * 4 + 0) * 256 + t] = x0 * r;
  prob[(b * 4 + 1) * 256 + t] = x1 * r;
  prob[(b * 4 + 2) * 256 + t] = x2 * r;
  prob[(b * 4 + 3) * 256 + t] = x3 * r;
}

// ---------------- Kernel B2: aggT[b][tap][o][c] bf16 = sum_k prob*weight ----------------
__global__ __launch_bounds__(256) void k_agg(
    const float* __restrict__ weight, const float* __restrict__ prob,
    unsigned short* __restrict__ aggT) {
  const int o = blockIdx.x, t = threadIdx.x;
  __shared__ float w[4][2304];
#pragma unroll
  for (int k = 0; k < 4; ++k) {
    const float4* src = (const float4*)(weight + (size_t)(k * 256 + o) * 2304);
    float4* dst = (float4*)w[k];
    for (int j = t; j < 576; j += 256) dst[j] = src[j];
  }
  __syncthreads();
  const int c = t;
  float wv[4][9];
#pragma unroll
  for (int k = 0; k < 4; ++k)
#pragma unroll
    for (int tap = 0; tap < 9; ++tap) wv[k][tap] = w[k][c * 9 + tap];
  for (int b = 0; b < 16; ++b) {
    float p0 = prob[(b * 4 + 0) * 256 + o];
    float p1 = prob[(b * 4 + 1) * 256 + o];
    float p2 = prob[(b * 4 + 2) * 256 + o];
    float p3 = prob[(b * 4 + 3) * 256 + o];
#pragma unroll
    for (int tap = 0; tap < 9; ++tap) {
      float vv = p0 * wv[0][tap] + p1 * wv[1][tap] + p2 * wv[2][tap] + p3 * wv[3][tap];
      aggT[((size_t)(b * 9 + tap) * 256 + o) * 256 + c] = f2bf(vv);
    }
  }
}

// ---------------- Kernel C: per-sample implicit-GEMM conv ----------------
// Tile: 128 pixels (2 rows x 64 cols) x 128 out-channels. 4 waves (2x2).
// K-loop: 4 c-chunks(64) x 9 taps x 2 MFMA K-steps (16x16x32 bf16).
// W pipeline: ring of 3 LDS buffers, prefetch depth 2, counted vmcnt(4) +
// raw s_barrier per tap (never vmcnt(0) mid-loop). XOR-swizzled LDS via
// pre-swizzled global source (both-sides involution).
// grid: 16 b * 32 ytile * 2 otile = 1024 blocks, 256 threads
__global__ __launch_bounds__(256, 2) void k_conv(
    const unsigned short* __restrict__ xn,
    const unsigned short* __restrict__ aggT,
    const unsigned short* __restrict__ zpage,
    float* __restrict__ out) {
  // XCD-aware swizzle: 1024 blocks = 8 XCDs x 128; each XCD owns 2 whole
  // samples -> aggT slice (2.4MB) L2-resident per XCD.
  const int bx0 = blockIdx.x;
  const int bx  = (bx0 & 7) * 128 + (bx0 >> 3);
  const int ot = bx & 1;
  const int yt = (bx >> 1) & 31;
  const int b  = bx >> 6;
  const int y0 = yt * 2;
  const int o0 = ot * 128;
  const int t    = threadIdx.x;
  const int lane = t & 63;
  const int l15  = lane & 15;
  const int lg   = lane >> 4;
  const int wid  = t >> 6;
  const int wm   = wid >> 1;   // pixel row of wave (0..1)
  const int wn   = wid & 1;    // ochan half (0..1)

  __shared__ unsigned short xbuf[256 * 64];      // 32 KiB
  __shared__ unsigned short wbuf[3][128 * 64];   // 3 x 16 KiB ring

  const f32x4 vzero = {0.f, 0.f, 0.f, 0.f};
  const bf16x8 bzero = {};
  f32x4 acc[4][4];
#pragma unroll
  for (int i = 0; i < 4; ++i)
#pragma unroll
    for (int j = 0; j < 4; ++j) acc[i][j] = vzero;

  const unsigned short* xb = xn + (size_t)b * (64 * 64 * 256);
  const unsigned short* ab = aggT + (size_t)b * (9 * 256 * 256) + (size_t)o0 * 256;

  for (int cc = 0; cc < 4; ++cc) {
    const int c0 = cc * 64;
    // stage X tile (2048 x 16B units), row halo -> zero page   [vm 0->8]
#pragma unroll
    for (int i = 0; i < 8; ++i) {
      int u = t + i * 256;
      int pos = u >> 3, s = u & 7;
      int rr = pos >> 6, xc = pos & 63;
      int yy = y0 - 1 + rr;
      int sp = (s ^ (pos & 7)) * 8;
      const unsigned short* src = (yy >= 0 && yy < 64)
          ? xb + ((size_t)yy * 64 + xc) * 256 + (c0 + sp)
          : zpage + ((u & 127) * 8);
      gload16(src, &xbuf[u * 8]);
    }
    // stage W tap0 -> buf0, tap1 -> buf1   [vm 8->16]
#pragma unroll
    for (int tp = 0; tp < 2; ++tp) {
      unsigned short* dst = wbuf[tp];
      const unsigned short* wsrc = ab + (size_t)tp * (256 * 256) + c0;
#pragma unroll
      for (int i = 0; i < 4; ++i) {
        int u = t + i * 256;
        int o = u >> 3, s = u & 7;
        gload16(wsrc + (size_t)o * 256 + ((s ^ (o & 7)) * 8), &dst[u * 8]);
      }
    }
    WAIT_VM(4);     // X + W0 done; W1 (4 newest) stays in flight
    BARRIER_PIN();

#pragma unroll
    for (int tap = 0; tap < 9; ++tap) {
      if (tap < 7) {   // prefetch W(tap+2); stays in flight across the barrier
        unsigned short* dst = wbuf[(tap + 2) % 3];
        const unsigned short* wsrc = ab + (size_t)(tap + 2) * (256 * 256) + c0;
#pragma unroll
        for (int i = 0; i < 4; ++i) {
          int u = t + i * 256;
          int o = u >> 3, s = u & 7;
          gload16(wsrc + (size_t)o * 256 + ((s ^ (o & 7)) * 8), &dst[u * 8]);
        }
      }
      const int kh = tap / 3;
      const int d  = tap % 3 - 1;
      const int prow = (wm + kh) * 64;
      const unsigned short* wb = wbuf[tap % 3];
#pragma unroll
      for (int ku = 0; ku < 2; ++ku) {
        bf16x8 av[4], bv[4];
#pragma unroll
        for (int mf = 0; mf < 4; ++mf) {
          int xsrc = mf * 16 + l15 + d;
          bool valid = (xsrc >= 0) && (xsrc < 64);
          int xcl = min(max(xsrc, 0), 63);
          int pos = prow + xcl;
          int su = (ku * 4 + lg) ^ (pos & 7);
          av[mf] = *(const bf16x8*)&xbuf[pos * 64 + su * 8];
          if (!valid) av[mf] = bzero;   // column halo -> 0
        }
#pragma unroll
        for (int nf = 0; nf < 4; ++nf) {
          int oo = wn * 64 + nf * 16 + l15;
          int su = (ku * 4 + lg) ^ (oo & 7);
          bv[nf] = *(const bf16x8*)&wb[oo * 64 + su * 8];
        }
        __builtin_amdgcn_s_setprio(1);
#pragma unroll
        for (int mf = 0; mf < 4; ++mf)
#pragma unroll
          for (int nf = 0; nf < 4; ++nf)
            acc[mf][nf] = __builtin_amdgcn_mfma_f32_16x16x32_bf16(av[mf], bv[nf], acc[mf][nf], 0, 0, 0);
        __builtin_amdgcn_s_setprio(0);
      }
      // drain W(tap+1) only (oldest 4); keep W(tap+2) in flight.
      // in-flight here: tap<7 -> {W(tap+1), W(tap+2)} = 8; tap==7 -> {W8}=4; tap==8 -> 0
      if (tap < 7) { WAIT_VM(4); } else { WAIT_VM(0); }
      BARRIER_PIN();   // after this, wbuf[(tap+1)%3] is readable by all waves
    }
  }

  // epilogue: D row = pixel = (lane>>4)*4 + reg, col = ochan = lane&15
  const int yrow = y0 + wm;
#pragma unroll
  for (int nf = 0; nf < 4; ++nf) {
    int och = o0 + wn * 64 + nf * 16 + l15;
    float* op = out + ((size_t)(b * 256 + och) * 4096) + yrow * 64;
#pragma unroll
    for (int mf = 0; mf < 4; ++mf) {
      int xcb = mf * 16 + lg * 4;
      *(float4*)(op + xcb) = *(float4*)&acc[mf][nf];
    }
  }
}

extern "C" void kernel_launch(void* const* d_in, const int* in_sizes, int n_in,
                              void* d_out, int out_size, void* d_ws, size_t ws_size,
                              hipStream_t stream) {
  (void)in_sizes; (void)n_in; (void)out_size; (void)ws_size;
  const float* x      = (const float*)d_in[0];
  const float* fc1    = (const float*)d_in[1];
  const float* fc2    = (const float*)d_in[2];
  const float* fc2b   = (const float*)d_in[3];
  const float* weight = (const float*)d_in[4];
  float* out = (float*)d_out;

  // workspace layout (~52.7 MB):
  //   [0,4K)            zero page (row-halo source for global_load_lds)
  //   [4K,20K)          pooled_sum f32[16][256]            (16,384 B)
  //   [20K, 86016)      prob f32[16][4][256]               (65,536 B)
  //   [131072, +18.87MB)  aggT bf16[16][9][256][256]       (18,874,368 B)
  //   [19,005,440, +33.55MB) x_nhwc bf16[16][64][64][256]  (33,554,432 B)
  char* ws = (char*)d_ws;
  unsigned short* zpage  = (unsigned short*)ws;
  float*          pooled = (float*)(ws + 4096);
  float*          prob   = (float*)(ws + 20480);
  unsigned short* aggT   = (unsigned short*)(ws + 131072);
  unsigned short* xnhwc  = (unsigned short*)(ws + 131072 + 18874368);

  hipMemsetAsync(d_ws, 0, 20480, stream);  // zero page + pooled_sum, every launch
  k_prep<<<dim3(16 * 4 * 64), dim3(256), 0, stream>>>(x, xnhwc, pooled);
  k_fc  <<<dim3(16),          dim3(256), 0, stream>>>(pooled, fc1, fc2, fc2b, prob);
  k_agg <<<dim3(256),         dim3(256), 0, stream>>>(weight, prob, aggT);
  k_conv<<<dim3(1024),        dim3(256), 0, stream>>>(xnhwc, aggT, zpage, out);
}